// Round 11
// baseline (3608.042 us; speedup 1.0000x reference)
//
#include <hip/hip_runtime.h>
#include <math.h>

#define S_ 512
#define B_ 128
#define D_ 512
#define I_ 64
#define F_ 2048
#define H_ 8
#define DK_ 64
#define L_ 4
#define SB_ (S_*B_)

typedef unsigned short u16;
typedef unsigned int u32;
typedef __attribute__((ext_vector_type(4))) unsigned int u32x4;
typedef __attribute__((ext_vector_type(4))) float f32x4;

__device__ __forceinline__ u16 f2bf(float f){
  u32 x = __builtin_bit_cast(u32, f);
  x += 0x7fffu + ((x >> 16) & 1u);
  return (u16)(x >> 16);
}

__device__ __forceinline__ void mfma16(f32x4& c, const u32x4& a, const u32x4& b){
  asm volatile("v_mfma_f32_16x16x32_bf16 %0, %1, %2, %0" : "+v"(c) : "v"(a), "v"(b));
}

// async global->LDS, 16 B per lane (m97 pattern)
__device__ __forceinline__ void gload16(const u16* g, u16* l){
  __builtin_amdgcn_global_load_lds((const __attribute__((address_space(1))) unsigned int*)g,
                                   (__attribute__((address_space(3))) unsigned int*)l, 16, 0, 0);
}

// fast GELU (tanh form): |err| vs exact erf-GELU <= ~1e-3, below bf16 ulp of act.
__device__ __forceinline__ float gelu_fast(float x){
  float u = 0.7978845608028654f * fmaf(0.044715f*x*x, x, x);
  float ae = __expf(-2.f*fabsf(u));
  float th = (1.f - ae) / (1.f + ae);
  th = (u < 0.f) ? -th : th;
  return 0.5f * x * (1.f + th);
}

// ---------------- positional encoding table ----------------
__global__ void pe_kernel(float* __restrict__ pe){
  int s = blockIdx.x, d = threadIdx.x;
  float e = expf((float)(d & ~1) * (-9.210340371976184f / (float)D_));
  float arg = (float)s * e;
  pe[s*D_ + d] = (d & 1) ? cosf(arg) : sinf(arg);
}

// ---------------- weight transpose + fp32->bf16 ----------------
__global__ void transpose_bf16(const float* __restrict__ src, u16* __restrict__ dst,
                               int R, int C, size_t zstride){
  __shared__ float t[32][33];
  size_t sbase = (size_t)blockIdx.z * R * C;
  size_t dbase = (size_t)blockIdx.z * zstride;
  int r0 = blockIdx.y*32, c0 = blockIdx.x*32;
  int tx = threadIdx.x, ty = threadIdx.y;
  #pragma unroll
  for (int j=0;j<4;j++)
    t[ty+j*8][tx] = src[sbase + (size_t)(r0+ty+j*8)*C + c0+tx];
  __syncthreads();
  #pragma unroll
  for (int j=0;j<4;j++)
    dst[dbase + (size_t)(c0+ty+j*8)*R + r0+tx] = f2bf(t[tx][ty+j*8]);
}

// ---------------- input projection + scale + PE ----------------
__global__ __launch_bounds__(512) void inproj_kernel(const float* __restrict__ x,
    const float* __restrict__ Win, const float* __restrict__ bin,
    const float* __restrict__ pe, float* __restrict__ h){
  __shared__ float xs[8][64];
  int t = threadIdx.x;           // = output column d
  float w[64];
  #pragma unroll
  for (int i=0;i<64;i++) w[i] = Win[i*D_ + t];
  float bd = bin[t];
  int r0 = blockIdx.x * 128;
  for (int batch=0; batch<16; batch++){
    int rb = r0 + batch*8;
    {
      int rr = t >> 6, i = t & 63;
      int r = rb + rr;
      int s = r >> 7, b = r & 127;
      xs[rr][i] = x[((size_t)b*S_ + s)*I_ + i];
    }
    __syncthreads();
    float acc[8];
    #pragma unroll
    for (int rr=0;rr<8;rr++) acc[rr] = 0.f;
    #pragma unroll
    for (int i4=0;i4<16;i4++){
      f32x4 xv[8];
      #pragma unroll
      for (int rr=0;rr<8;rr++) xv[rr] = *(const f32x4*)&xs[rr][i4*4];
      #pragma unroll
      for (int rr=0;rr<8;rr++){
        acc[rr] = fmaf(xv[rr][0], w[i4*4+0], acc[rr]);
        acc[rr] = fmaf(xv[rr][1], w[i4*4+1], acc[rr]);
        acc[rr] = fmaf(xv[rr][2], w[i4*4+2], acc[rr]);
        acc[rr] = fmaf(xv[rr][3], w[i4*4+3], acc[rr]);
      }
    }
    #pragma unroll
    for (int rr=0;rr<8;rr++){
      int r = rb + rr;
      int s = r >> 7;
      h[(size_t)r*D_ + t] = (acc[rr] + bd) * 22.627416997969522f + pe[s*D_ + t];
    }
    __syncthreads();
  }
}

// ---------------- LayerNorm ----------------
template<int FINAL>
__global__ __launch_bounds__(256) void ln_kernel(const float* __restrict__ hsrc,
    const float* __restrict__ g, const float* __restrict__ bb,
    u16* __restrict__ outb, float* __restrict__ outf){
  int row = blockIdx.x*4 + (threadIdx.x>>6);
  int lane = threadIdx.x & 63;
  const float* hr = hsrc + (size_t)row*D_ + lane*8;
  f32x4 a0 = *(const f32x4*)hr;
  f32x4 a1 = *(const f32x4*)(hr+4);
  float v[8];
  #pragma unroll
  for (int j=0;j<4;j++){ v[j]=a0[j]; v[4+j]=a1[j]; }
  float sum = 0.f;
  #pragma unroll
  for (int j=0;j<8;j++) sum += v[j];
  #pragma unroll
  for (int m=1;m<64;m<<=1) sum += __shfl_xor(sum, m);
  float mean = sum * (1.f/(float)D_);
  float s2 = 0.f;
  #pragma unroll
  for (int j=0;j<8;j++){ float dd = v[j]-mean; s2 = fmaf(dd,dd,s2); }
  #pragma unroll
  for (int m=1;m<64;m<<=1) s2 += __shfl_xor(s2, m);
  float inv = rsqrtf(s2*(1.f/(float)D_) + 1e-5f);
  f32x4 g0 = *(const f32x4*)&g[lane*8];
  f32x4 g1 = *(const f32x4*)&g[lane*8+4];
  f32x4 b0 = *(const f32x4*)&bb[lane*8];
  f32x4 b1 = *(const f32x4*)&bb[lane*8+4];
  float o[8];
  #pragma unroll
  for (int j=0;j<4;j++){
    o[j]   = (v[j]-mean)*inv*g0[j] + b0[j];
    o[4+j] = (v[4+j]-mean)*inv*g1[j] + b1[j];
  }
  if (FINAL == 0){
    u32x4 pk;
    #pragma unroll
    for (int j=0;j<4;j++)
      pk[j] = (u32)f2bf(o[2*j]) | ((u32)f2bf(o[2*j+1])<<16);
    *(u32x4*)&outb[(size_t)row*D_ + lane*8] = pk;
  } else {
    int s = row>>7, b = row&(B_-1);
    float* op = outf + ((size_t)b*S_ + s)*D_ + lane*8;
    f32x4 r0, r1;
    #pragma unroll
    for (int j=0;j<4;j++){ r0[j]=o[j]; r1[j]=o[4+j]; }
    *(f32x4*)op = r0;
    *(f32x4*)(op+4) = r1;
  }
}

// ======== 256x256 bf16 MFMA GEMM, 8-phase counted-vmcnt schedule (m201) =====
// 8 waves (2Mx4N), per-wave output 128x64 = acc[8][4]. LDS 128 KiB:
// [2 dbuf][A,B][2 khalf][256 rows x 32 cols]. Staging unit = one 16 KB chunk
// (2 x gload16/thread). Per iteration (2 K-tiles, 8 phases), phase =
// {8x ds_read frags | stage 1 chunk -> barrier -> lgkmcnt(0)+sched_barrier ->
// setprio(1) -> 16 MFMA -> setprio(0) -> [vmcnt] -> barrier}.
// Stage order ph1..8: A1,B1(k+1) A0,B0(k+2) A1,B1(k+2) A0,B0(k+3);
// vmcnt(4) only at ph4/ph8 (ph4 tightens to vmcnt(0) on the final iteration
// where ph3/4 stages are skipped). Region safety: every chunk overwrite is
// issued >=1 barrier after the last read of its old contents (checked per
// phase). Slot-XOR swizzle per 32-col chunk (both-sides, rule #21):
// phys slot = logical ^ ((row>>1)&3); source pre-swizzled, read XORed.
// MODE 0: QKV fused N=1536 scatter; MODE 1: hres += val+bias; MODE 2: gelu.
template<int MODE>
__global__ __launch_bounds__(512, 2) void gemm8p(const u16* __restrict__ A,
    const u16* __restrict__ Wt, const float* __restrict__ bias,
    float* __restrict__ hres, u16* __restrict__ outb, int N, int K){
  const u32 nwg = gridDim.x * gridDim.y;
  u32 wg = blockIdx.y * gridDim.x + blockIdx.x;
  wg = (wg & 7) * (nwg >> 3) + (wg >> 3);   // bijective XCD swizzle (nwg%8==0)
  const int m0 = (int)(wg / gridDim.x) * 256;
  const int n0 = (int)(wg % gridDim.x) * 256;
  __shared__ u16 lds[2][2][2][8192];        // [dbuf][mat][khalf][256*32]
  const int t = threadIdx.x;
  const int lane = t & 63, wave = t >> 6;
  const int wm = wave >> 2, wn = wave & 3;  // 2 M-waves x 4 N-waves
  const int rsel = lane & 15;
  const int pslot = (((lane>>4) ^ ((rsel>>1)&3))) * 8;  // u16 offs in 32-col row
  const int sl = (t&3) ^ ((t>>3)&3);        // pre-swizzled source slot
  const u16* ag = A  + (size_t)(m0 + (t>>2))*K + sl*8;
  const u16* bg = Wt + (size_t)(n0 + (t>>2))*K + sl*8;
  const int NT = K >> 6;                    // 64-wide K-tiles (NT even, >=8)
  auto stage = [&](int mat, int kt, int kh){
    const u16* g = (mat ? bg : ag) + kt*64 + kh*32;
    u16* dst = &lds[kt & 1][mat][kh][t*8];
    gload16(g,                  dst);
    gload16(g + (size_t)128*K,  dst + 4096);
  };
  f32x4 acc[8][4] = {};
  // prologue: A0,B0(0), A1,B1(0), A0,B0(1); first 4 chunks must land.
  stage(0,0,0); stage(1,0,0); stage(0,0,1); stage(1,0,1); stage(0,1,0); stage(1,1,0);
  asm volatile("s_waitcnt vmcnt(4)" ::: "memory");
  __builtin_amdgcn_s_barrier();

#define PHASE(DB, KH, MH, SMAT, STILE, SKH, CHK) { \
    u32x4 af[4], bf[4]; \
    _Pragma("unroll") \
    for (int i=0;i<4;i++) \
      af[i] = *(const u32x4*)&lds[DB][0][KH][(wm*128 + MH*64 + i*16 + rsel)*32 + pslot]; \
    _Pragma("unroll") \
    for (int j=0;j<4;j++) \
      bf[j] = *(const u32x4*)&lds[DB][1][KH][(wn*64 + j*16 + rsel)*32 + pslot]; \
    if ((STILE) < NT) stage(SMAT, STILE, SKH); \
    __builtin_amdgcn_s_barrier(); \
    asm volatile("s_waitcnt lgkmcnt(0)" ::: "memory"); \
    __builtin_amdgcn_sched_barrier(0); \
    __builtin_amdgcn_s_setprio(1); \
    _Pragma("unroll") \
    for (int i=0;i<4;i++) \
      _Pragma("unroll") \
      for (int j=0;j<4;j++) \
        mfma16(acc[(MH)*4+i][j], af[i], bf[j]); \
    __builtin_amdgcn_s_setprio(0); \
    if ((CHK) == 1){ \
      if (i2 + 2 < NT) asm volatile("s_waitcnt vmcnt(4)" ::: "memory"); \
      else             asm volatile("s_waitcnt vmcnt(0)" ::: "memory"); \
    } else if ((CHK) == 2){ \
      asm volatile("s_waitcnt vmcnt(4)" ::: "memory"); \
    } \
    __builtin_amdgcn_s_barrier(); }

  for (int i2 = 0; i2 < NT; i2 += 2){
    PHASE(0, 0, 0, 0, i2+1, 1, 0)   // ph1: stage A1(k+1)
    PHASE(0, 0, 1, 1, i2+1, 1, 0)   // ph2: stage B1(k+1)
    PHASE(0, 1, 0, 0, i2+2, 0, 0)   // ph3: stage A0(k+2)
    PHASE(0, 1, 1, 1, i2+2, 0, 1)   // ph4: stage B0(k+2); vmcnt
    PHASE(1, 0, 0, 0, i2+2, 1, 0)   // ph5: stage A1(k+2)
    PHASE(1, 0, 1, 1, i2+2, 1, 0)   // ph6: stage B1(k+2)
    PHASE(1, 1, 0, 0, i2+3, 0, 0)   // ph7: stage A0(k+3)
    PHASE(1, 1, 1, 1, i2+3, 0, 2)   // ph8: stage B0(k+3); vmcnt
  }
#undef PHASE
  asm volatile("s_nop 7\n\ts_nop 7");
  const int rb = (lane>>4)*4;
  #pragma unroll
  for (int i8=0;i8<8;i8++){
    #pragma unroll
    for (int j=0;j<4;j++){
      int gn = n0 + wn*64 + j*16 + rsel;
      #pragma unroll
      for (int rg=0;rg<4;rg++){
        int gr = m0 + wm*128 + (i8>>2)*64 + (i8&3)*16 + rb + rg;
        float val = acc[i8][j][rg];
        if (MODE == 0){
          int mat = gn >> 9;
          int hh = (gn >> 6) & 7, dd = gn & 63;
          int s = gr >> 7, b = gr & 127;
          u16* dst = outb + (size_t)mat*33554432ull;
          dst[(size_t)((s*H_ + hh)*B_ + b)*DK_ + dd] = f2bf(val);
        } else if (MODE == 1){
          hres[(size_t)gr*D_ + gn] += val + bias[gn];
        } else {
          outb[(size_t)gr*(size_t)N + gn] = f2bf(gelu_fast(val + bias[gn]));
        }
      }
    }
  }
}

// ---------------- fused batch-attention per (s, head) ----------------
// MFMA PV; all register arrays statically indexed (rule #20).
__global__ __launch_bounds__(256, 2) void attn_kernel(const u16* __restrict__ qb,
    const u16* __restrict__ kb, const u16* __restrict__ vb, u16* __restrict__ cb){
  __shared__ __align__(16) char smem[80384];
  u16* q_lds = (u16*)smem;                 // [128][72]
  u16* k_lds = (u16*)(smem + 18432);       // [128][72]
  float* S   = (float*)smem;               // [128][132] f32, overlays q,k
  u16* P     = (u16*)smem;                 // [128][136] bf16, overlays dead S
  u16* vT    = (u16*)(smem + 34816);       // [64][136], overlays dead S
  u32* wl    = (u32*)(smem + 67584);       // [256][12] packed (bf16 w | idx)
  float* rs  = (float*)(smem + 79872);     // [128] inverse row sums
  int sh = blockIdx.x;
  int s = sh >> 3, hh = sh & 7;
  int t = threadIdx.x, lane = t & 63, wave = t >> 6;
  const u16* qg = qb + (size_t)sh * (B_*DK_);
  const u16* kg = kb + (size_t)sh * (B_*DK_);
  const u16* vg = vb + (size_t)sh * (B_*DK_);
  #pragma unroll
  for (int rr=0; rr<4; rr++){
    int idx = rr*2048 + t*8;
    int row = idx >> 6, col = idx & 63;
    *(u32x4*)&q_lds[row*72+col] = *(const u32x4*)&qg[idx];
    *(u32x4*)&k_lds[row*72+col] = *(const u32x4*)&kg[idx];
  }
  __syncthreads();
  int wm = wave>>1, wn = wave&1, rsel = lane & 15;
  f32x4 sacc[4][4] = {};
  #pragma unroll
  for (int ks=0; ks<2; ks++){
    asm volatile("s_nop 7\n\ts_nop 7");
    int ko = ks*32 + (lane>>4)*8;
    u32x4 qf[4], kf[4];
    #pragma unroll
    for (int i=0;i<4;i++){
      qf[i] = *(const u32x4*)&q_lds[(wm*64+i*16+rsel)*72 + ko];
      kf[i] = *(const u32x4*)&k_lds[(wn*64+i*16+rsel)*72 + ko];
    }
    #pragma unroll
    for (int i=0;i<4;i++)
      #pragma unroll
      for (int j=0;j<4;j++)
        mfma16(sacc[i][j], qf[i], kf[j]);
  }
  asm volatile("s_nop 7\n\ts_nop 7");
  __syncthreads();  // MFMA reads of q,k complete before S overlays them
  int rb = (lane>>4)*4;
  #pragma unroll
  for (int i=0;i<4;i++)
    #pragma unroll
    for (int j=0;j<4;j++)
      #pragma unroll
      for (int rg=0;rg<4;rg++)
        S[(wm*64+i*16+rb+rg)*132 + wn*64+j*16+rsel] = sacc[i][j][rg] * 0.125f;
  __syncthreads();
  // ---- per-row top-12 (2 threads/row, 64 elems each), vectorized reads ----
  int r = t >> 1, half = t & 1;
  const f32x4* srow4 = (const f32x4*)(S + r*132 + half*64);
  float kv[12];
  #pragma unroll
  for (int i=0;i<12;i++) kv[i] = -3.4e38f;
  for (int i4=0;i4<16;i4++){
    f32x4 v4 = srow4[i4];
    float m4 = fmaxf(fmaxf(v4[0],v4[1]), fmaxf(v4[2],v4[3]));
    if (m4 > kv[11]){
      #pragma unroll
      for (int z=0; z<4; z++){
        float inc = v4[z];
        if (inc > kv[11]){
          #pragma unroll
          for (int p=0;p<12;p++){
            float cur = kv[p];
            bool gt = inc > cur;
            kv[p] = gt ? inc : cur;
            inc   = gt ? cur : inc;
          }
        }
      }
    }
  }
  float kth = 3.4e38f;
  #pragma unroll
  for (int i=0;i<12;i++){
    float pb = __shfl_xor(kv[11-i], 1);
    kth = fminf(kth, fmaxf(kv[i], pb));
  }
  float mx = fmaxf(kv[0], __shfl_xor(kv[0], 1));
  // ---- exp + compact winners into wl ----
  float sum = 0.f;
  int n = 0;
  u32* myw = wl + t*12;
  for (int i4=0;i4<16;i4++){
    f32x4 v4 = srow4[i4];
    #pragma unroll
    for (int z=0; z<4; z++){
      float v = v4[z];
      if (v >= kth && n < 12){
        float e = __expf(v - mx);
        sum += e;
        myw[n] = ((u32)f2bf(e) << 16) | (u32)(half*64 + i4*4 + z);
        n++;
      }
    }
  }
  float tsum = sum + __shfl_xor(sum, 1);
  if (!half) rs[r] = 1.f / tsum;
  __syncthreads();           // S fully consumed by all threads
  // ---- zero P + stage V^T (both overlay dead S; disjoint regions) ----
  {
    u32x4 zz = {0u,0u,0u,0u};
    #pragma unroll
    for (int z=0; z<9; z++){
      int idx = z*256 + t;
      if (idx < 2176) ((u32x4*)P)[idx] = zz;
    }
  }
  #pragma unroll
  for (int rr=0; rr<16; rr++){
    int idx2 = (rr*256 + t)*2;
    u32 u = *(const u32*)&vg[idx2];
    int c = idx2 >> 6, d0 = idx2 & 63;
    vT[d0*136 + c]     = (u16)(u & 0xffffu);
    vT[(d0+1)*136 + c] = (u16)(u >> 16);
  }
  __syncthreads();
  // ---- scatter winners into P ----
  u16* prow = P + r*136;
  for (int j=0; j<n; j++){
    u32 e = myw[j];
    prow[e & 0xffffu] = (u16)(e >> 16);
  }
  __syncthreads();
  // ---- PV MFMA: ctx[128][64] = P[128][128] @ V[128][64] ----
  f32x4 cacc[4][2] = {};
  #pragma unroll
  for (int ks=0; ks<4; ks++){
    asm volatile("s_nop 7\n\ts_nop 7");
    int ko = ks*32 + (lane>>4)*8;
    u32x4 pf[4], vf[2];
    #pragma unroll
    for (int i=0;i<4;i++) pf[i] = *(const u32x4*)&P[(wm*64+i*16+rsel)*136 + ko];
    #pragma unroll
    for (int j=0;j<2;j++) vf[j] = *(const u32x4*)&vT[(wn*32+j*16+rsel)*136 + ko];
    #pragma unroll
    for (int i=0;i<4;i++)
      #pragma unroll
      for (int j=0;j<2;j++)
        mfma16(cacc[i][j], pf[i], vf[j]);
  }
  asm volatile("s_nop 7\n\ts_nop 7");
  #pragma unroll
  for (int i=0;i<4;i++)
    #pragma unroll
    for (int j=0;j<2;j++)
      #pragma unroll
      for (int rg=0;rg<4;rg++){
        int m = wm*64 + i*16 + rb + rg;
        int nn = wn*32 + j*16 + rsel;
        float val = cacc[i][j][rg] * rs[m];
        cb[((size_t)(s*B_ + m))*D_ + hh*DK_ + nn] = f2bf(val);
      }
}

extern "C" void kernel_launch(void* const* d_in, const int* in_sizes, int n_in,
                              void* d_out, int out_size, void* d_ws, size_t ws_size,
                              hipStream_t stream) {
  const float* x    = (const float*)d_in[0];
  const float* Win  = (const float*)d_in[1];
  const float* bin  = (const float*)d_in[2];
  const float* ln1g = (const float*)d_in[3];
  const float* ln1b = (const float*)d_in[4];
  const float* Wq   = (const float*)d_in[5];
  const float* Wk   = (const float*)d_in[6];
  const float* Wv   = (const float*)d_in[7];
  const float* Wo   = (const float*)d_in[8];
  const float* bo   = (const float*)d_in[9];
  const float* ln2g = (const float*)d_in[10];
  const float* ln2b = (const float*)d_in[11];
  const float* W1   = (const float*)d_in[12];
  const float* b1   = (const float*)d_in[13];
  const float* W2   = (const float*)d_in[14];
  const float* b2   = (const float*)d_in[15];
  const float* lnfg = (const float*)d_in[16];
  const float* lnfb = (const float*)d_in[17];

  char* ws = (char*)d_ws;
  float* h  = (float*)(ws);                      // 134217728 B
  u16* yb   = (u16*)(ws + 134217728ull);         // 67108864 B
  u16* qb   = (u16*)(ws + 201326592ull);         // q,k,v contiguous
  u16* kb   = (u16*)(ws + 268435456ull);
  u16* vb   = (u16*)(ws + 335544320ull);
  u16* cb   = (u16*)(ws + 402653184ull);
  u16* act  = qb;                                // overlays qb..cb
  u16* wqkvT= (u16*)(ws + 469762048ull);         // [L][3][D][D] = 6 MB
  u16* woT  = (u16*)(ws + 476053504ull);         // [L][D][D] = 2 MB
  u16* w1T  = (u16*)(ws + 478150656ull);         // 8 MB
  u16* w2T  = (u16*)(ws + 486539264ull);         // 8 MB
  float* pe = (float*)(ws + 494927872ull);       // 1 MB

  dim3 tb(32,8);
  pe_kernel<<<S_, D_, 0, stream>>>(pe);
  transpose_bf16<<<dim3(D_/32, D_/32, L_), tb, 0, stream>>>(Wq, wqkvT,            D_, D_, (size_t)3*D_*D_);
  transpose_bf16<<<dim3(D_/32, D_/32, L_), tb, 0, stream>>>(Wk, wqkvT + D_*D_,    D_, D_, (size_t)3*D_*D_);
  transpose_bf16<<<dim3(D_/32, D_/32, L_), tb, 0, stream>>>(Wv, wqkvT + 2*D_*D_,  D_, D_, (size_t)3*D_*D_);
  transpose_bf16<<<dim3(D_/32, D_/32, L_), tb, 0, stream>>>(Wo, woT,              D_, D_, (size_t)D_*D_);
  transpose_bf16<<<dim3(F_/32, D_/32, L_), tb, 0, stream>>>(W1, w1T, D_, F_, (size_t)D_*F_);
  transpose_bf16<<<dim3(D_/32, F_/32, L_), tb, 0, stream>>>(W2, w2T, F_, D_, (size_t)F_*D_);
  inproj_kernel<<<512, 512, 0, stream>>>(x, Win, bin, pe, h);

  ln_kernel<0><<<SB_/4, 256, 0, stream>>>(h, ln1g, ln1b, yb, nullptr);  // ln1[0]
  for (int l=0; l<L_; l++){
    gemm8p<0><<<dim3(6,256), 512, 0, stream>>>(yb, wqkvT + (size_t)l*3*D_*D_, nullptr, nullptr, qb, 1536, D_);
    attn_kernel<<<S_*H_, 256, 0, stream>>>(qb, kb, vb, cb);
    gemm8p<1><<<dim3(2,256), 512, 0, stream>>>(cb, woT + (size_t)l*D_*D_, bo + l*D_, h, nullptr, D_, D_);
    ln_kernel<0><<<SB_/4, 256, 0, stream>>>(h, ln2g + l*D_, ln2b + l*D_, yb, nullptr);
    gemm8p<2><<<dim3(8,256), 512, 0, stream>>>(yb, w1T + (size_t)l*D_*F_, b1 + l*F_, nullptr, act, F_, D_);
    gemm8p<1><<<dim3(2,256), 512, 0, stream>>>(act, w2T + (size_t)l*F_*D_, b2 + l*D_, h, nullptr, D_, F_);
    if (l < L_-1)
      ln_kernel<0><<<SB_/4, 256, 0, stream>>>(h, ln1g + (l+1)*D_, ln1b + (l+1)*D_, yb, nullptr);
  }
  ln_kernel<1><<<SB_/4, 256, 0, stream>>>(h, lnfg, lnfb, nullptr, (float*)d_out);
}

// Round 12
// 3445.252 us; speedup vs baseline: 1.0473x; 1.0473x over previous
//
#include <hip/hip_runtime.h>
#include <math.h>

#define S_ 512
#define B_ 128
#define D_ 512
#define I_ 64
#define F_ 2048
#define H_ 8
#define DK_ 64
#define L_ 4
#define SB_ (S_*B_)

typedef unsigned short u16;
typedef unsigned int u32;
typedef __attribute__((ext_vector_type(4))) unsigned int u32x4;
typedef __attribute__((ext_vector_type(4))) float f32x4;

__device__ __forceinline__ u16 f2bf(float f){
  u32 x = __builtin_bit_cast(u32, f);
  x += 0x7fffu + ((x >> 16) & 1u);
  return (u16)(x >> 16);
}

__device__ __forceinline__ void mfma16(f32x4& c, const u32x4& a, const u32x4& b){
  asm volatile("v_mfma_f32_16x16x32_bf16 %0, %1, %2, %0" : "+v"(c) : "v"(a), "v"(b));
}

// async global->LDS, 16 B per lane (m97 pattern)
__device__ __forceinline__ void gload16(const u16* g, u16* l){
  __builtin_amdgcn_global_load_lds((const __attribute__((address_space(1))) unsigned int*)g,
                                   (__attribute__((address_space(3))) unsigned int*)l, 16, 0, 0);
}

// fast GELU (tanh form): |err| vs exact erf-GELU <= ~1e-3, below bf16 ulp of act.
__device__ __forceinline__ float gelu_fast(float x){
  float u = 0.7978845608028654f * fmaf(0.044715f*x*x, x, x);
  float ae = __expf(-2.f*fabsf(u));
  float th = (1.f - ae) / (1.f + ae);
  th = (u < 0.f) ? -th : th;
  return 0.5f * x * (1.f + th);
}

// ---------------- positional encoding table ----------------
__global__ void pe_kernel(float* __restrict__ pe){
  int s = blockIdx.x, d = threadIdx.x;
  float e = expf((float)(d & ~1) * (-9.210340371976184f / (float)D_));
  float arg = (float)s * e;
  pe[s*D_ + d] = (d & 1) ? cosf(arg) : sinf(arg);
}

// ---------------- weight transpose + fp32->bf16 ----------------
__global__ void transpose_bf16(const float* __restrict__ src, u16* __restrict__ dst,
                               int R, int C, size_t zstride){
  __shared__ float t[32][33];
  size_t sbase = (size_t)blockIdx.z * R * C;
  size_t dbase = (size_t)blockIdx.z * zstride;
  int r0 = blockIdx.y*32, c0 = blockIdx.x*32;
  int tx = threadIdx.x, ty = threadIdx.y;
  #pragma unroll
  for (int j=0;j<4;j++)
    t[ty+j*8][tx] = src[sbase + (size_t)(r0+ty+j*8)*C + c0+tx];
  __syncthreads();
  #pragma unroll
  for (int j=0;j<4;j++)
    dst[dbase + (size_t)(c0+ty+j*8)*R + r0+tx] = f2bf(t[tx][ty+j*8]);
}

// ---------------- input projection + scale + PE ----------------
__global__ __launch_bounds__(512) void inproj_kernel(const float* __restrict__ x,
    const float* __restrict__ Win, const float* __restrict__ bin,
    const float* __restrict__ pe, float* __restrict__ h){
  __shared__ float xs[8][64];
  int t = threadIdx.x;           // = output column d
  float w[64];
  #pragma unroll
  for (int i=0;i<64;i++) w[i] = Win[i*D_ + t];
  float bd = bin[t];
  int r0 = blockIdx.x * 128;
  for (int batch=0; batch<16; batch++){
    int rb = r0 + batch*8;
    {
      int rr = t >> 6, i = t & 63;
      int r = rb + rr;
      int s = r >> 7, b = r & 127;
      xs[rr][i] = x[((size_t)b*S_ + s)*I_ + i];
    }
    __syncthreads();
    float acc[8];
    #pragma unroll
    for (int rr=0;rr<8;rr++) acc[rr] = 0.f;
    #pragma unroll
    for (int i4=0;i4<16;i4++){
      f32x4 xv[8];
      #pragma unroll
      for (int rr=0;rr<8;rr++) xv[rr] = *(const f32x4*)&xs[rr][i4*4];
      #pragma unroll
      for (int rr=0;rr<8;rr++){
        acc[rr] = fmaf(xv[rr][0], w[i4*4+0], acc[rr]);
        acc[rr] = fmaf(xv[rr][1], w[i4*4+1], acc[rr]);
        acc[rr] = fmaf(xv[rr][2], w[i4*4+2], acc[rr]);
        acc[rr] = fmaf(xv[rr][3], w[i4*4+3], acc[rr]);
      }
    }
    #pragma unroll
    for (int rr=0;rr<8;rr++){
      int r = rb + rr;
      int s = r >> 7;
      h[(size_t)r*D_ + t] = (acc[rr] + bd) * 22.627416997969522f + pe[s*D_ + t];
    }
    __syncthreads();
  }
}

// ---------------- LayerNorm ----------------
template<int FINAL>
__global__ __launch_bounds__(256) void ln_kernel(const float* __restrict__ hsrc,
    const float* __restrict__ g, const float* __restrict__ bb,
    u16* __restrict__ outb, float* __restrict__ outf){
  int row = blockIdx.x*4 + (threadIdx.x>>6);
  int lane = threadIdx.x & 63;
  const float* hr = hsrc + (size_t)row*D_ + lane*8;
  f32x4 a0 = *(const f32x4*)hr;
  f32x4 a1 = *(const f32x4*)(hr+4);
  float v[8];
  #pragma unroll
  for (int j=0;j<4;j++){ v[j]=a0[j]; v[4+j]=a1[j]; }
  float sum = 0.f;
  #pragma unroll
  for (int j=0;j<8;j++) sum += v[j];
  #pragma unroll
  for (int m=1;m<64;m<<=1) sum += __shfl_xor(sum, m);
  float mean = sum * (1.f/(float)D_);
  float s2 = 0.f;
  #pragma unroll
  for (int j=0;j<8;j++){ float dd = v[j]-mean; s2 = fmaf(dd,dd,s2); }
  #pragma unroll
  for (int m=1;m<64;m<<=1) s2 += __shfl_xor(s2, m);
  float inv = rsqrtf(s2*(1.f/(float)D_) + 1e-5f);
  f32x4 g0 = *(const f32x4*)&g[lane*8];
  f32x4 g1 = *(const f32x4*)&g[lane*8+4];
  f32x4 b0 = *(const f32x4*)&bb[lane*8];
  f32x4 b1 = *(const f32x4*)&bb[lane*8+4];
  float o[8];
  #pragma unroll
  for (int j=0;j<4;j++){
    o[j]   = (v[j]-mean)*inv*g0[j] + b0[j];
    o[4+j] = (v[4+j]-mean)*inv*g1[j] + b1[j];
  }
  if (FINAL == 0){
    u32x4 pk;
    #pragma unroll
    for (int j=0;j<4;j++)
      pk[j] = (u32)f2bf(o[2*j]) | ((u32)f2bf(o[2*j+1])<<16);
    *(u32x4*)&outb[(size_t)row*D_ + lane*8] = pk;
  } else {
    int s = row>>7, b = row&(B_-1);
    float* op = outf + ((size_t)b*S_ + s)*D_ + lane*8;
    f32x4 r0, r1;
    #pragma unroll
    for (int j=0;j<4;j++){ r0[j]=o[j]; r1[j]=o[4+j]; }
    *(f32x4*)op = r0;
    *(f32x4*)(op+4) = r1;
  }
}

// ----- 128x256 (MxN) bf16 MFMA GEMM, BK=64, 8 waves, 2-phase (r10 lineage) --
// r11 post-mortem: 8-phase/1-block-per-CU ports lose inter-block TLP (r7,r11
// both ~265-270 vs r10's 220). This keeps r10's proven 2-phase structure and
// doubles MFMA work per barrier-drain instead: 8 waves (2Mx4N), wave tile
// 64x64 (acc[4][4] = same 64 VGPR as r10), stage 48 KB per K-step (1.5x) for
// 2x MFMA. LDS 48 KB -> 3 blocks/CU. B-panel HBM re-fetch halves.
// Slot-XOR swizzle (both-sides, rule #21; r8-proven conflicts->0): logical
// 16B-slot s of row r at physical s^(r&7); source pre-swizzled, read XORed.
// MODE 0: QKV fused N=1536 scatter; MODE 1: hres += val+bias; MODE 2: gelu.
template<int MODE>
__global__ __launch_bounds__(512) void gemm128(const u16* __restrict__ A,
    const u16* __restrict__ Wt, const float* __restrict__ bias,
    float* __restrict__ hres, u16* __restrict__ outb, int N, int K){
  const u32 nwg = gridDim.x * gridDim.y;
  u32 wg = blockIdx.y * gridDim.x + blockIdx.x;
  wg = (wg & 7) * (nwg >> 3) + (wg >> 3);   // bijective (nwg%8==0)
  const int m0 = (int)(wg / gridDim.x) * 128;
  const int n0 = (int)(wg % gridDim.x) * 256;
  __shared__ u16 a_lds[128*64];   // 16 KB
  __shared__ u16 b_lds[256*64];   // 32 KB
  const int t = threadIdx.x;
  const int lane = t & 63, wave = t >> 6;
  const int wm = wave >> 2, wn = wave & 3;  // 2 M-waves x 4 N-waves
  const int rsel = lane & 15;
  // read: logical slot = ks*4 + (lane>>4); physical = logical ^ (rsel&7)
  const int kp0 = (((lane>>4)    ) ^ (rsel&7)) * 8;
  const int kp1 = (((lane>>4) | 4) ^ (rsel&7)) * 8;
  // stage: thread t covers phys chunk (row (t>>3)+64p, slot t&7) from logical
  // slot (t&7)^((t>>3)&7)  (row&7 == (t>>3)&7 since passes are +64)
  const int sl = (t&7) ^ ((t>>3)&7);
  const u16* ag = A  + (size_t)(m0 + (t>>3))*K + sl*8;
  const u16* bg = Wt + (size_t)(n0 + (t>>3))*K + sl*8;
  f32x4 acc[4][4] = {};
  for (int k0 = 0; k0 < K; k0 += 64){
    asm volatile("s_nop 7\n\ts_nop 7"); // WAR insurance before LDS overwrite
    __syncthreads();
    #pragma unroll
    for (int p=0;p<2;p++)
      gload16(ag + (size_t)(p*64)*K + k0, &a_lds[p*4096 + t*8]);
    #pragma unroll
    for (int p=0;p<4;p++)
      gload16(bg + (size_t)(p*64)*K + k0, &b_lds[p*4096 + t*8]);
    __syncthreads();
    u32x4 af[4], bfr[4];
    #pragma unroll
    for (int i=0;i<4;i++){
      af[i]  = *(const u32x4*)&a_lds[(wm*64 + i*16 + rsel)*64 + kp0];
      bfr[i] = *(const u32x4*)&b_lds[(wn*64 + i*16 + rsel)*64 + kp0];
    }
    #pragma unroll
    for (int i=0;i<4;i++)
      #pragma unroll
      for (int j=0;j<4;j++)
        mfma16(acc[i][j], af[i], bfr[j]);
    #pragma unroll
    for (int i=0;i<4;i++){
      af[i]  = *(const u32x4*)&a_lds[(wm*64 + i*16 + rsel)*64 + kp1];
      bfr[i] = *(const u32x4*)&b_lds[(wn*64 + i*16 + rsel)*64 + kp1];
    }
    #pragma unroll
    for (int i=0;i<4;i++)
      #pragma unroll
      for (int j=0;j<4;j++)
        mfma16(acc[i][j], af[i], bfr[j]);
  }
  asm volatile("s_nop 7\n\ts_nop 7");
  const int rb = (lane>>4)*4;
  #pragma unroll
  for (int i=0;i<4;i++){
    #pragma unroll
    for (int j=0;j<4;j++){
      int gn = n0 + wn*64 + j*16 + rsel;
      #pragma unroll
      for (int rg=0;rg<4;rg++){
        int gr = m0 + wm*64 + i*16 + rb + rg;
        float val = acc[i][j][rg];
        if (MODE == 0){
          int mat = gn >> 9;
          int hh = (gn >> 6) & 7, dd = gn & 63;
          int s = gr >> 7, b = gr & 127;
          u16* dst = outb + (size_t)mat*33554432ull;
          dst[(size_t)((s*H_ + hh)*B_ + b)*DK_ + dd] = f2bf(val);
        } else if (MODE == 1){
          hres[(size_t)gr*D_ + gn] += val + bias[gn];
        } else {
          outb[(size_t)gr*(size_t)N + gn] = f2bf(gelu_fast(val + bias[gn]));
        }
      }
    }
  }
}

// ---------------- fused batch-attention per (s, head) ----------------
// MFMA PV; all register arrays statically indexed (rule #20).
__global__ __launch_bounds__(256, 2) void attn_kernel(const u16* __restrict__ qb,
    const u16* __restrict__ kb, const u16* __restrict__ vb, u16* __restrict__ cb){
  __shared__ __align__(16) char smem[80384];
  u16* q_lds = (u16*)smem;                 // [128][72]
  u16* k_lds = (u16*)(smem + 18432);       // [128][72]
  float* S   = (float*)smem;               // [128][132] f32, overlays q,k
  u16* P     = (u16*)smem;                 // [128][136] bf16, overlays dead S
  u16* vT    = (u16*)(smem + 34816);       // [64][136], overlays dead S
  u32* wl    = (u32*)(smem + 67584);       // [256][12] packed (bf16 w | idx)
  float* rs  = (float*)(smem + 79872);     // [128] inverse row sums
  int sh = blockIdx.x;
  int s = sh >> 3, hh = sh & 7;
  int t = threadIdx.x, lane = t & 63, wave = t >> 6;
  const u16* qg = qb + (size_t)sh * (B_*DK_);
  const u16* kg = kb + (size_t)sh * (B_*DK_);
  const u16* vg = vb + (size_t)sh * (B_*DK_);
  #pragma unroll
  for (int rr=0; rr<4; rr++){
    int idx = rr*2048 + t*8;
    int row = idx >> 6, col = idx & 63;
    *(u32x4*)&q_lds[row*72+col] = *(const u32x4*)&qg[idx];
    *(u32x4*)&k_lds[row*72+col] = *(const u32x4*)&kg[idx];
  }
  __syncthreads();
  int wm = wave>>1, wn = wave&1, rsel = lane & 15;
  f32x4 sacc[4][4] = {};
  #pragma unroll
  for (int ks=0; ks<2; ks++){
    asm volatile("s_nop 7\n\ts_nop 7");
    int ko = ks*32 + (lane>>4)*8;
    u32x4 qf[4], kf[4];
    #pragma unroll
    for (int i=0;i<4;i++){
      qf[i] = *(const u32x4*)&q_lds[(wm*64+i*16+rsel)*72 + ko];
      kf[i] = *(const u32x4*)&k_lds[(wn*64+i*16+rsel)*72 + ko];
    }
    #pragma unroll
    for (int i=0;i<4;i++)
      #pragma unroll
      for (int j=0;j<4;j++)
        mfma16(sacc[i][j], qf[i], kf[j]);
  }
  asm volatile("s_nop 7\n\ts_nop 7");
  __syncthreads();  // MFMA reads of q,k complete before S overlays them
  int rb = (lane>>4)*4;
  #pragma unroll
  for (int i=0;i<4;i++)
    #pragma unroll
    for (int j=0;j<4;j++)
      #pragma unroll
      for (int rg=0;rg<4;rg++)
        S[(wm*64+i*16+rb+rg)*132 + wn*64+j*16+rsel] = sacc[i][j][rg] * 0.125f;
  __syncthreads();
  // ---- per-row top-12 (2 threads/row, 64 elems each), vectorized reads ----
  int r = t >> 1, half = t & 1;
  const f32x4* srow4 = (const f32x4*)(S + r*132 + half*64);
  float kv[12];
  #pragma unroll
  for (int i=0;i<12;i++) kv[i] = -3.4e38f;
  for (int i4=0;i4<16;i4++){
    f32x4 v4 = srow4[i4];
    float m4 = fmaxf(fmaxf(v4[0],v4[1]), fmaxf(v4[2],v4[3]));
    if (m4 > kv[11]){
      #pragma unroll
      for (int z=0; z<4; z++){
        float inc = v4[z];
        if (inc > kv[11]){
          #pragma unroll
          for (int p=0;p<12;p++){
            float cur = kv[p];
            bool gt = inc > cur;
            kv[p] = gt ? inc : cur;
            inc   = gt ? cur : inc;
          }
        }
      }
    }
  }
  float kth = 3.4e38f;
  #pragma unroll
  for (int i=0;i<12;i++){
    float pb = __shfl_xor(kv[11-i], 1);
    kth = fminf(kth, fmaxf(kv[i], pb));
  }
  float mx = fmaxf(kv[0], __shfl_xor(kv[0], 1));
  // ---- exp + compact winners into wl ----
  float sum = 0.f;
  int n = 0;
  u32* myw = wl + t*12;
  for (int i4=0;i4<16;i4++){
    f32x4 v4 = srow4[i4];
    #pragma unroll
    for (int z=0; z<4; z++){
      float v = v4[z];
      if (v >= kth && n < 12){
        float e = __expf(v - mx);
        sum += e;
        myw[n] = ((u32)f2bf(e) << 16) | (u32)(half*64 + i4*4 + z);
        n++;
      }
    }
  }
  float tsum = sum + __shfl_xor(sum, 1);
  if (!half) rs[r] = 1.f / tsum;
  __syncthreads();           // S fully consumed by all threads
  // ---- zero P + stage V^T (both overlay dead S; disjoint regions) ----
  {
    u32x4 zz = {0u,0u,0u,0u};
    #pragma unroll
    for (int z=0; z<9; z++){
      int idx = z*256 + t;
      if (idx < 2176) ((u32x4*)P)[idx] = zz;
    }
  }
  #pragma unroll
  for (int rr=0; rr<16; rr++){
    int idx2 = (rr*256 + t)*2;
    u32 u = *(const u32*)&vg[idx2];
    int c = idx2 >> 6, d0 = idx2 & 63;
    vT[d0*136 + c]     = (u16)(u & 0xffffu);
    vT[(d0+1)*136 + c] = (u16)(u >> 16);
  }
  __syncthreads();
  // ---- scatter winners into P ----
  u16* prow = P + r*136;
  for (int j=0; j<n; j++){
    u32 e = myw[j];
    prow[e & 0xffffu] = (u16)(e >> 16);
  }
  __syncthreads();
  // ---- PV MFMA: ctx[128][64] = P[128][128] @ V[128][64] ----
  f32x4 cacc[4][2] = {};
  #pragma unroll
  for (int ks=0; ks<4; ks++){
    asm volatile("s_nop 7\n\ts_nop 7");
    int ko = ks*32 + (lane>>4)*8;
    u32x4 pf[4], vf[2];
    #pragma unroll
    for (int i=0;i<4;i++) pf[i] = *(const u32x4*)&P[(wm*64+i*16+rsel)*136 + ko];
    #pragma unroll
    for (int j=0;j<2;j++) vf[j] = *(const u32x4*)&vT[(wn*32+j*16+rsel)*136 + ko];
    #pragma unroll
    for (int i=0;i<4;i++)
      #pragma unroll
      for (int j=0;j<2;j++)
        mfma16(cacc[i][j], pf[i], vf[j]);
  }
  asm volatile("s_nop 7\n\ts_nop 7");
  #pragma unroll
  for (int i=0;i<4;i++)
    #pragma unroll
    for (int j=0;j<2;j++)
      #pragma unroll
      for (int rg=0;rg<4;rg++){
        int m = wm*64 + i*16 + rb + rg;
        int nn = wn*32 + j*16 + rsel;
        float val = cacc[i][j][rg] * rs[m];
        cb[((size_t)(s*B_ + m))*D_ + hh*DK_ + nn] = f2bf(val);
      }
}

extern "C" void kernel_launch(void* const* d_in, const int* in_sizes, int n_in,
                              void* d_out, int out_size, void* d_ws, size_t ws_size,
                              hipStream_t stream) {
  const float* x    = (const float*)d_in[0];
  const float* Win  = (const float*)d_in[1];
  const float* bin  = (const float*)d_in[2];
  const float* ln1g = (const float*)d_in[3];
  const float* ln1b = (const float*)d_in[4];
  const float* Wq   = (const float*)d_in[5];
  const float* Wk   = (const float*)d_in[6];
  const float* Wv   = (const float*)d_in[7];
  const float* Wo   = (const float*)d_in[8];
  const float* bo   = (const float*)d_in[9];
  const float* ln2g = (const float*)d_in[10];
  const float* ln2b = (const float*)d_in[11];
  const float* W1   = (const float*)d_in[12];
  const float* b1   = (const float*)d_in[13];
  const float* W2   = (const float*)d_in[14];
  const float* b2   = (const float*)d_in[15];
  const float* lnfg = (const float*)d_in[16];
  const float* lnfb = (const float*)d_in[17];

  char* ws = (char*)d_ws;
  float* h  = (float*)(ws);                      // 134217728 B
  u16* yb   = (u16*)(ws + 134217728ull);         // 67108864 B
  u16* qb   = (u16*)(ws + 201326592ull);         // q,k,v contiguous
  u16* kb   = (u16*)(ws + 268435456ull);
  u16* vb   = (u16*)(ws + 335544320ull);
  u16* cb   = (u16*)(ws + 402653184ull);
  u16* act  = qb;                                // overlays qb..cb
  u16* wqkvT= (u16*)(ws + 469762048ull);         // [L][3][D][D] = 6 MB
  u16* woT  = (u16*)(ws + 476053504ull);         // [L][D][D] = 2 MB
  u16* w1T  = (u16*)(ws + 478150656ull);         // 8 MB
  u16* w2T  = (u16*)(ws + 486539264ull);         // 8 MB
  float* pe = (float*)(ws + 494927872ull);       // 1 MB

  dim3 tb(32,8);
  pe_kernel<<<S_, D_, 0, stream>>>(pe);
  transpose_bf16<<<dim3(D_/32, D_/32, L_), tb, 0, stream>>>(Wq, wqkvT,            D_, D_, (size_t)3*D_*D_);
  transpose_bf16<<<dim3(D_/32, D_/32, L_), tb, 0, stream>>>(Wk, wqkvT + D_*D_,    D_, D_, (size_t)3*D_*D_);
  transpose_bf16<<<dim3(D_/32, D_/32, L_), tb, 0, stream>>>(Wv, wqkvT + 2*D_*D_,  D_, D_, (size_t)3*D_*D_);
  transpose_bf16<<<dim3(D_/32, D_/32, L_), tb, 0, stream>>>(Wo, woT,              D_, D_, (size_t)D_*D_);
  transpose_bf16<<<dim3(F_/32, D_/32, L_), tb, 0, stream>>>(W1, w1T, D_, F_, (size_t)D_*F_);
  transpose_bf16<<<dim3(D_/32, F_/32, L_), tb, 0, stream>>>(W2, w2T, F_, D_, (size_t)F_*D_);
  inproj_kernel<<<512, 512, 0, stream>>>(x, Win, bin, pe, h);

  ln_kernel<0><<<SB_/4, 256, 0, stream>>>(h, ln1g, ln1b, yb, nullptr);  // ln1[0]
  for (int l=0; l<L_; l++){
    gemm128<0><<<dim3(6,512), 512, 0, stream>>>(yb, wqkvT + (size_t)l*3*D_*D_, nullptr, nullptr, qb, 1536, D_);
    attn_kernel<<<S_*H_, 256, 0, stream>>>(qb, kb, vb, cb);
    gemm128<1><<<dim3(2,512), 512, 0, stream>>>(cb, woT + (size_t)l*D_*D_, bo + l*D_, h, nullptr, D_, D_);
    ln_kernel<0><<<SB_/4, 256, 0, stream>>>(h, ln2g + l*D_, ln2b + l*D_, yb, nullptr);
    gemm128<2><<<dim3(8,512), 512, 0, stream>>>(yb, w1T + (size_t)l*D_*F_, b1 + l*F_, nullptr, act, F_, D_);
    gemm128<1><<<dim3(2,512), 512, 0, stream>>>(act, w2T + (size_t)l*F_*D_, b2 + l*D_, h, nullptr, D_, F_);
    if (l < L_-1)
      ln_kernel<0><<<SB_/4, 256, 0, stream>>>(h, ln1g + (l+1)*D_, ln1b + (l+1)*D_, yb, nullptr);
  }
  ln_kernel<1><<<SB_/4, 256, 0, stream>>>(h, lnfg, lnfb, nullptr, (float*)d_out);
}

// Round 13
// 3417.966 us; speedup vs baseline: 1.0556x; 1.0080x over previous
//
#include <hip/hip_runtime.h>
#include <math.h>

#define S_ 512
#define B_ 128
#define D_ 512
#define I_ 64
#define F_ 2048
#define H_ 8
#define DK_ 64
#define L_ 4
#define SB_ (S_*B_)

typedef unsigned short u16;
typedef unsigned int u32;
typedef __attribute__((ext_vector_type(4))) unsigned int u32x4;
typedef __attribute__((ext_vector_type(4))) float f32x4;

__device__ __forceinline__ u16 f2bf(float f){
  u32 x = __builtin_bit_cast(u32, f);
  x += 0x7fffu + ((x >> 16) & 1u);
  return (u16)(x >> 16);
}

__device__ __forceinline__ void mfma16(f32x4& c, const u32x4& a, const u32x4& b){
  asm volatile("v_mfma_f32_16x16x32_bf16 %0, %1, %2, %0" : "+v"(c) : "v"(a), "v"(b));
}

// async global->LDS, 16 B per lane (m97 pattern)
__device__ __forceinline__ void gload16(const u16* g, u16* l){
  __builtin_amdgcn_global_load_lds((const __attribute__((address_space(1))) unsigned int*)g,
                                   (__attribute__((address_space(3))) unsigned int*)l, 16, 0, 0);
}

// fast GELU (tanh form): |err| vs exact erf-GELU <= ~1e-3, below bf16 ulp of act.
__device__ __forceinline__ float gelu_fast(float x){
  float u = 0.7978845608028654f * fmaf(0.044715f*x*x, x, x);
  float ae = __expf(-2.f*fabsf(u));
  float th = (1.f - ae) / (1.f + ae);
  th = (u < 0.f) ? -th : th;
  return 0.5f * x * (1.f + th);
}

// ---------------- positional encoding table ----------------
__global__ void pe_kernel(float* __restrict__ pe){
  int s = blockIdx.x, d = threadIdx.x;
  float e = expf((float)(d & ~1) * (-9.210340371976184f / (float)D_));
  float arg = (float)s * e;
  pe[s*D_ + d] = (d & 1) ? cosf(arg) : sinf(arg);
}

// ---------------- weight transpose + fp32->bf16 ----------------
__global__ void transpose_bf16(const float* __restrict__ src, u16* __restrict__ dst,
                               int R, int C, size_t zstride){
  __shared__ float t[32][33];
  size_t sbase = (size_t)blockIdx.z * R * C;
  size_t dbase = (size_t)blockIdx.z * zstride;
  int r0 = blockIdx.y*32, c0 = blockIdx.x*32;
  int tx = threadIdx.x, ty = threadIdx.y;
  #pragma unroll
  for (int j=0;j<4;j++)
    t[ty+j*8][tx] = src[sbase + (size_t)(r0+ty+j*8)*C + c0+tx];
  __syncthreads();
  #pragma unroll
  for (int j=0;j<4;j++)
    dst[dbase + (size_t)(c0+ty+j*8)*R + r0+tx] = f2bf(t[tx][ty+j*8]);
}

// ---------------- input projection + scale + PE ----------------
__global__ __launch_bounds__(512) void inproj_kernel(const float* __restrict__ x,
    const float* __restrict__ Win, const float* __restrict__ bin,
    const float* __restrict__ pe, float* __restrict__ h){
  __shared__ float xs[8][64];
  int t = threadIdx.x;           // = output column d
  float w[64];
  #pragma unroll
  for (int i=0;i<64;i++) w[i] = Win[i*D_ + t];
  float bd = bin[t];
  int r0 = blockIdx.x * 128;
  for (int batch=0; batch<16; batch++){
    int rb = r0 + batch*8;
    {
      int rr = t >> 6, i = t & 63;
      int r = rb + rr;
      int s = r >> 7, b = r & 127;
      xs[rr][i] = x[((size_t)b*S_ + s)*I_ + i];
    }
    __syncthreads();
    float acc[8];
    #pragma unroll
    for (int rr=0;rr<8;rr++) acc[rr] = 0.f;
    #pragma unroll
    for (int i4=0;i4<16;i4++){
      f32x4 xv[8];
      #pragma unroll
      for (int rr=0;rr<8;rr++) xv[rr] = *(const f32x4*)&xs[rr][i4*4];
      #pragma unroll
      for (int rr=0;rr<8;rr++){
        acc[rr] = fmaf(xv[rr][0], w[i4*4+0], acc[rr]);
        acc[rr] = fmaf(xv[rr][1], w[i4*4+1], acc[rr]);
        acc[rr] = fmaf(xv[rr][2], w[i4*4+2], acc[rr]);
        acc[rr] = fmaf(xv[rr][3], w[i4*4+3], acc[rr]);
      }
    }
    #pragma unroll
    for (int rr=0;rr<8;rr++){
      int r = rb + rr;
      int s = r >> 7;
      h[(size_t)r*D_ + t] = (acc[rr] + bd) * 22.627416997969522f + pe[s*D_ + t];
    }
    __syncthreads();
  }
}

// ---------------- LayerNorm ----------------
template<int FINAL>
__global__ __launch_bounds__(256) void ln_kernel(const float* __restrict__ hsrc,
    const float* __restrict__ g, const float* __restrict__ bb,
    u16* __restrict__ outb, float* __restrict__ outf){
  int row = blockIdx.x*4 + (threadIdx.x>>6);
  int lane = threadIdx.x & 63;
  const float* hr = hsrc + (size_t)row*D_ + lane*8;
  f32x4 a0 = *(const f32x4*)hr;
  f32x4 a1 = *(const f32x4*)(hr+4);
  float v[8];
  #pragma unroll
  for (int j=0;j<4;j++){ v[j]=a0[j]; v[4+j]=a1[j]; }
  float sum = 0.f;
  #pragma unroll
  for (int j=0;j<8;j++) sum += v[j];
  #pragma unroll
  for (int m=1;m<64;m<<=1) sum += __shfl_xor(sum, m);
  float mean = sum * (1.f/(float)D_);
  float s2 = 0.f;
  #pragma unroll
  for (int j=0;j<8;j++){ float dd = v[j]-mean; s2 = fmaf(dd,dd,s2); }
  #pragma unroll
  for (int m=1;m<64;m<<=1) s2 += __shfl_xor(s2, m);
  float inv = rsqrtf(s2*(1.f/(float)D_) + 1e-5f);
  f32x4 g0 = *(const f32x4*)&g[lane*8];
  f32x4 g1 = *(const f32x4*)&g[lane*8+4];
  f32x4 b0 = *(const f32x4*)&bb[lane*8];
  f32x4 b1 = *(const f32x4*)&bb[lane*8+4];
  float o[8];
  #pragma unroll
  for (int j=0;j<4;j++){
    o[j]   = (v[j]-mean)*inv*g0[j] + b0[j];
    o[4+j] = (v[4+j]-mean)*inv*g1[j] + b1[j];
  }
  if (FINAL == 0){
    u32x4 pk;
    #pragma unroll
    for (int j=0;j<4;j++)
      pk[j] = (u32)f2bf(o[2*j]) | ((u32)f2bf(o[2*j+1])<<16);
    *(u32x4*)&outb[(size_t)row*D_ + lane*8] = pk;
  } else {
    int s = row>>7, b = row&(B_-1);
    float* op = outf + ((size_t)b*S_ + s)*D_ + lane*8;
    f32x4 r0, r1;
    #pragma unroll
    for (int j=0;j<4;j++){ r0[j]=o[j]; r1[j]=o[4+j]; }
    *(f32x4*)op = r0;
    *(f32x4*)(op+4) = r1;
  }
}

// ----- 128x256 (MxN) bf16 MFMA GEMM, BK=64, 8 waves, 2-phase -----
// Used for QKV / Wo / FFN2 (r12: best measured for these shapes).
// Slot-XOR swizzle (both-sides, rule #21; r8-proven conflicts->0).
// MODE 0: QKV fused N=1536 scatter; MODE 1: hres += val+bias; MODE 2: gelu.
template<int MODE>
__global__ __launch_bounds__(512) void gemm256n(const u16* __restrict__ A,
    const u16* __restrict__ Wt, const float* __restrict__ bias,
    float* __restrict__ hres, u16* __restrict__ outb, int N, int K){
  const u32 nwg = gridDim.x * gridDim.y;
  u32 wg = blockIdx.y * gridDim.x + blockIdx.x;
  wg = (wg & 7) * (nwg >> 3) + (wg >> 3);   // bijective (nwg%8==0)
  const int m0 = (int)(wg / gridDim.x) * 128;
  const int n0 = (int)(wg % gridDim.x) * 256;
  __shared__ u16 a_lds[128*64];   // 16 KB
  __shared__ u16 b_lds[256*64];   // 32 KB
  const int t = threadIdx.x;
  const int lane = t & 63, wave = t >> 6;
  const int wm = wave >> 2, wn = wave & 3;  // 2 M-waves x 4 N-waves
  const int rsel = lane & 15;
  const int kp0 = (((lane>>4)    ) ^ (rsel&7)) * 8;
  const int kp1 = (((lane>>4) | 4) ^ (rsel&7)) * 8;
  const int sl = (t&7) ^ ((t>>3)&7);
  const u16* ag = A  + (size_t)(m0 + (t>>3))*K + sl*8;
  const u16* bg = Wt + (size_t)(n0 + (t>>3))*K + sl*8;
  f32x4 acc[4][4] = {};
  for (int k0 = 0; k0 < K; k0 += 64){
    asm volatile("s_nop 7\n\ts_nop 7"); // WAR insurance before LDS overwrite
    __syncthreads();
    #pragma unroll
    for (int p=0;p<2;p++)
      gload16(ag + (size_t)(p*64)*K + k0, &a_lds[p*4096 + t*8]);
    #pragma unroll
    for (int p=0;p<4;p++)
      gload16(bg + (size_t)(p*64)*K + k0, &b_lds[p*4096 + t*8]);
    __syncthreads();
    u32x4 af[4], bfr[4];
    #pragma unroll
    for (int i=0;i<4;i++){
      af[i]  = *(const u32x4*)&a_lds[(wm*64 + i*16 + rsel)*64 + kp0];
      bfr[i] = *(const u32x4*)&b_lds[(wn*64 + i*16 + rsel)*64 + kp0];
    }
    #pragma unroll
    for (int i=0;i<4;i++)
      #pragma unroll
      for (int j=0;j<4;j++)
        mfma16(acc[i][j], af[i], bfr[j]);
    #pragma unroll
    for (int i=0;i<4;i++){
      af[i]  = *(const u32x4*)&a_lds[(wm*64 + i*16 + rsel)*64 + kp1];
      bfr[i] = *(const u32x4*)&b_lds[(wn*64 + i*16 + rsel)*64 + kp1];
    }
    #pragma unroll
    for (int i=0;i<4;i++)
      #pragma unroll
      for (int j=0;j<4;j++)
        mfma16(acc[i][j], af[i], bfr[j]);
  }
  asm volatile("s_nop 7\n\ts_nop 7");
  const int rb = (lane>>4)*4;
  #pragma unroll
  for (int i=0;i<4;i++){
    #pragma unroll
    for (int j=0;j<4;j++){
      int gn = n0 + wn*64 + j*16 + rsel;
      #pragma unroll
      for (int rg=0;rg<4;rg++){
        int gr = m0 + wm*64 + i*16 + rb + rg;
        float val = acc[i][j][rg];
        if (MODE == 0){
          int mat = gn >> 9;
          int hh = (gn >> 6) & 7, dd = gn & 63;
          int s = gr >> 7, b = gr & 127;
          u16* dst = outb + (size_t)mat*33554432ull;
          dst[(size_t)((s*H_ + hh)*B_ + b)*DK_ + dd] = f2bf(val);
        } else if (MODE == 1){
          hres[(size_t)gr*D_ + gn] += val + bias[gn];
        } else {
          outb[(size_t)gr*(size_t)N + gn] = f2bf(gelu_fast(val + bias[gn]));
        }
      }
    }
  }
}

// ----- 128x128 bf16 MFMA GEMM, BK=64, 4 waves (r10 config; FFN1 best) -----
// 32 KB LDS -> 5 blocks/CU of inter-block TLP (measured 220 us for FFN1 vs
// 237 at 128x256). Same slot-XOR swizzle.
template<int MODE>
__global__ __launch_bounds__(256) void gemm4w(const u16* __restrict__ A,
    const u16* __restrict__ Wt, const float* __restrict__ bias,
    float* __restrict__ hres, u16* __restrict__ outb, int N, int K){
  const u32 nwg = gridDim.x * gridDim.y;
  u32 wg = blockIdx.y * gridDim.x + blockIdx.x;
  wg = (wg & 7) * (nwg >> 3) + (wg >> 3);   // bijective (nwg%8==0)
  const int m0 = (int)(wg / gridDim.x) * 128;
  const int n0 = (int)(wg % gridDim.x) * 128;
  __shared__ u16 a_lds[128*64];   // 16 KB
  __shared__ u16 b_lds[128*64];   // 16 KB
  const int t = threadIdx.x;
  const int lane = t & 63, wave = t >> 6;
  const int wm = wave >> 1, wn = wave & 1;
  const int rsel = lane & 15;
  const int kp0 = (((lane>>4)    ) ^ (rsel&7)) * 8;
  const int kp1 = (((lane>>4) | 4) ^ (rsel&7)) * 8;
  const int sl = (t&7) ^ ((t>>3)&7);
  const u16* ag = A  + (size_t)(m0 + (t>>3))*K + sl*8;
  const u16* bg = Wt + (size_t)(n0 + (t>>3))*K + sl*8;
  f32x4 acc[4][4] = {};
  for (int k0 = 0; k0 < K; k0 += 64){
    asm volatile("s_nop 7\n\ts_nop 7"); // WAR insurance before LDS overwrite
    __syncthreads();
    #pragma unroll
    for (int p=0;p<4;p++){
      gload16(ag + (size_t)(p*32)*K + k0, &a_lds[p*2048 + t*8]);
      gload16(bg + (size_t)(p*32)*K + k0, &b_lds[p*2048 + t*8]);
    }
    __syncthreads();
    u32x4 af[4], bfr[4];
    #pragma unroll
    for (int i=0;i<4;i++){
      af[i]  = *(const u32x4*)&a_lds[(wm*64 + i*16 + rsel)*64 + kp0];
      bfr[i] = *(const u32x4*)&b_lds[(wn*64 + i*16 + rsel)*64 + kp0];
    }
    #pragma unroll
    for (int i=0;i<4;i++)
      #pragma unroll
      for (int j=0;j<4;j++)
        mfma16(acc[i][j], af[i], bfr[j]);
    #pragma unroll
    for (int i=0;i<4;i++){
      af[i]  = *(const u32x4*)&a_lds[(wm*64 + i*16 + rsel)*64 + kp1];
      bfr[i] = *(const u32x4*)&b_lds[(wn*64 + i*16 + rsel)*64 + kp1];
    }
    #pragma unroll
    for (int i=0;i<4;i++)
      #pragma unroll
      for (int j=0;j<4;j++)
        mfma16(acc[i][j], af[i], bfr[j]);
  }
  asm volatile("s_nop 7\n\ts_nop 7");
  const int rb = (lane>>4)*4;
  #pragma unroll
  for (int i=0;i<4;i++){
    #pragma unroll
    for (int j=0;j<4;j++){
      int gn = n0 + wn*64 + j*16 + rsel;
      #pragma unroll
      for (int rg=0;rg<4;rg++){
        int gr = m0 + wm*64 + i*16 + rb + rg;
        float val = acc[i][j][rg];
        if (MODE == 0){
          int mat = gn >> 9;
          int hh = (gn >> 6) & 7, dd = gn & 63;
          int s = gr >> 7, b = gr & 127;
          u16* dst = outb + (size_t)mat*33554432ull;
          dst[(size_t)((s*H_ + hh)*B_ + b)*DK_ + dd] = f2bf(val);
        } else if (MODE == 1){
          hres[(size_t)gr*D_ + gn] += val + bias[gn];
        } else {
          outb[(size_t)gr*(size_t)N + gn] = f2bf(gelu_fast(val + bias[gn]));
        }
      }
    }
  }
}

// ---------------- fused batch-attention per (s, head) ----------------
// r12->r13: (T14) V loaded into registers at kernel start (contiguous 64B/
// thread; the intervening __syncthreads prevent sinking, so HBM latency hides
// under QK^T+topk); P-zeroing made thread-local (each thread zeros its OWN
// row-half = exactly where its winners scatter; cols 128..135 never read by
// PV) -> one barrier eliminated. All register arrays statically indexed.
__global__ __launch_bounds__(256, 2) void attn_kernel(const u16* __restrict__ qb,
    const u16* __restrict__ kb, const u16* __restrict__ vb, u16* __restrict__ cb){
  __shared__ __align__(16) char smem[80384];
  u16* q_lds = (u16*)smem;                 // [128][72]
  u16* k_lds = (u16*)(smem + 18432);       // [128][72]
  float* S   = (float*)smem;               // [128][132] f32, overlays q,k
  u16* P     = (u16*)smem;                 // [128][136] bf16, overlays dead S
  u16* vT    = (u16*)(smem + 34816);       // [64][136], overlays dead S
  u32* wl    = (u32*)(smem + 67584);       // [256][12] packed (bf16 w | idx)
  float* rs  = (float*)(smem + 79872);     // [128] inverse row sums
  int sh = blockIdx.x;
  int s = sh >> 3, hh = sh & 7;
  int t = threadIdx.x, lane = t & 63, wave = t >> 6;
  const u16* qg = qb + (size_t)sh * (B_*DK_);
  const u16* kg = kb + (size_t)sh * (B_*DK_);
  const u16* vg = vb + (size_t)sh * (B_*DK_);
  // early V load (T14): 64 B/thread, consumed only after topk
  u32x4 vr0 = *(const u32x4*)&vg[t*32];
  u32x4 vr1 = *(const u32x4*)&vg[t*32 + 8];
  u32x4 vr2 = *(const u32x4*)&vg[t*32 + 16];
  u32x4 vr3 = *(const u32x4*)&vg[t*32 + 24];
  #pragma unroll
  for (int rr=0; rr<4; rr++){
    int idx = rr*2048 + t*8;
    int row = idx >> 6, col = idx & 63;
    *(u32x4*)&q_lds[row*72+col] = *(const u32x4*)&qg[idx];
    *(u32x4*)&k_lds[row*72+col] = *(const u32x4*)&kg[idx];
  }
  __syncthreads();
  int wm = wave>>1, wn = wave&1, rsel = lane & 15;
  f32x4 sacc[4][4] = {};
  #pragma unroll
  for (int ks=0; ks<2; ks++){
    asm volatile("s_nop 7\n\ts_nop 7");
    int ko = ks*32 + (lane>>4)*8;
    u32x4 qf[4], kf[4];
    #pragma unroll
    for (int i=0;i<4;i++){
      qf[i] = *(const u32x4*)&q_lds[(wm*64+i*16+rsel)*72 + ko];
      kf[i] = *(const u32x4*)&k_lds[(wn*64+i*16+rsel)*72 + ko];
    }
    #pragma unroll
    for (int i=0;i<4;i++)
      #pragma unroll
      for (int j=0;j<4;j++)
        mfma16(sacc[i][j], qf[i], kf[j]);
  }
  asm volatile("s_nop 7\n\ts_nop 7");
  __syncthreads();  // MFMA reads of q,k complete before S overlays them
  int rb = (lane>>4)*4;
  #pragma unroll
  for (int i=0;i<4;i++)
    #pragma unroll
    for (int j=0;j<4;j++)
      #pragma unroll
      for (int rg=0;rg<4;rg++)
        S[(wm*64+i*16+rb+rg)*132 + wn*64+j*16+rsel] = sacc[i][j][rg] * 0.125f;
  __syncthreads();
  // ---- per-row top-12 (2 threads/row, 64 elems each), vectorized reads ----
  int r = t >> 1, half = t & 1;
  const f32x4* srow4 = (const f32x4*)(S + r*132 + half*64);
  float kv[12];
  #pragma unroll
  for (int i=0;i<12;i++) kv[i] = -3.4e38f;
  for (int i4=0;i4<16;i4++){
    f32x4 v4 = srow4[i4];
    float m4 = fmaxf(fmaxf(v4[0],v4[1]), fmaxf(v4[2],v4[3]));
    if (m4 > kv[11]){
      #pragma unroll
      for (int z=0; z<4; z++){
        float inc = v4[z];
        if (inc > kv[11]){
          #pragma unroll
          for (int p=0;p<12;p++){
            float cur = kv[p];
            bool gt = inc > cur;
            kv[p] = gt ? inc : cur;
            inc   = gt ? cur : inc;
          }
        }
      }
    }
  }
  float kth = 3.4e38f;
  #pragma unroll
  for (int i=0;i<12;i++){
    float pb = __shfl_xor(kv[11-i], 1);
    kth = fminf(kth, fmaxf(kv[i], pb));
  }
  float mx = fmaxf(kv[0], __shfl_xor(kv[0], 1));
  // ---- exp + compact winners into wl ----
  float sum = 0.f;
  int n = 0;
  u32* myw = wl + t*12;
  for (int i4=0;i4<16;i4++){
    f32x4 v4 = srow4[i4];
    #pragma unroll
    for (int z=0; z<4; z++){
      float v = v4[z];
      if (v >= kth && n < 12){
        float e = __expf(v - mx);
        sum += e;
        myw[n] = ((u32)f2bf(e) << 16) | (u32)(half*64 + i4*4 + z);
        n++;
      }
    }
  }
  float tsum = sum + __shfl_xor(sum, 1);
  if (!half) rs[r] = 1.f / tsum;
  __syncthreads();           // ALL threads done reading S before P overlays it
  // ---- zero OWN P row-half (cols half*64..+63; where our winners land) ----
  {
    u32x4 zz = {0u,0u,0u,0u};
    u16* pz = P + r*136 + half*64;
    #pragma unroll
    for (int z=0; z<8; z++) ((u32x4*)pz)[z] = zz;
  }
  // ---- scatter winners into own row (no barrier needed: same thread) ----
  u16* prow = P + r*136;
  for (int j=0; j<n; j++){
    u32 e = myw[j];
    prow[e & 0xffffu] = (u16)(e >> 16);
  }
  // ---- write V^T from preloaded registers ----
  #pragma unroll
  for (int q4=0; q4<4; q4++){
    u32 u0 = (q4==0?vr0[0]:q4==1?vr1[0]:q4==2?vr2[0]:vr3[0]);
    u32 u1 = (q4==0?vr0[1]:q4==1?vr1[1]:q4==2?vr2[1]:vr3[1]);
    u32 u2 = (q4==0?vr0[2]:q4==1?vr1[2]:q4==2?vr2[2]:vr3[2]);
    u32 u3 = (q4==0?vr0[3]:q4==1?vr1[3]:q4==2?vr2[3]:vr3[3]);
    u32 uu[4] = {u0,u1,u2,u3};
    #pragma unroll
    for (int z=0; z<4; z++){
      int idx2 = t*32 + q4*8 + z*2;
      int c = idx2 >> 6, d0 = idx2 & 63;
      vT[d0*136 + c]     = (u16)(uu[z] & 0xffffu);
      vT[(d0+1)*136 + c] = (u16)(uu[z] >> 16);
    }
  }
  __syncthreads();
  // ---- PV MFMA: ctx[128][64] = P[128][128] @ V[128][64] ----
  f32x4 cacc[4][2] = {};
  #pragma unroll
  for (int ks=0; ks<4; ks++){
    asm volatile("s_nop 7\n\ts_nop 7");
    int ko = ks*32 + (lane>>4)*8;
    u32x4 pf[4], vf[2];
    #pragma unroll
    for (int i=0;i<4;i++) pf[i] = *(const u32x4*)&P[(wm*64+i*16+rsel)*136 + ko];
    #pragma unroll
    for (int j=0;j<2;j++) vf[j] = *(const u32x4*)&vT[(wn*32+j*16+rsel)*136 + ko];
    #pragma unroll
    for (int i=0;i<4;i++)
      #pragma unroll
      for (int j=0;j<2;j++)
        mfma16(cacc[i][j], pf[i], vf[j]);
  }
  asm volatile("s_nop 7\n\ts_nop 7");
  #pragma unroll
  for (int i=0;i<4;i++)
    #pragma unroll
    for (int j=0;j<2;j++)
      #pragma unroll
      for (int rg=0;rg<4;rg++){
        int m = wm*64 + i*16 + rb + rg;
        int nn = wn*32 + j*16 + rsel;
        float val = cacc[i][j][rg] * rs[m];
        cb[((size_t)(s*B_ + m))*D_ + hh*DK_ + nn] = f2bf(val);
      }
}

extern "C" void kernel_launch(void* const* d_in, const int* in_sizes, int n_in,
                              void* d_out, int out_size, void* d_ws, size_t ws_size,
                              hipStream_t stream) {
  const float* x    = (const float*)d_in[0];
  const float* Win  = (const float*)d_in[1];
  const float* bin  = (const float*)d_in[2];
  const float* ln1g = (const float*)d_in[3];
  const float* ln1b = (const float*)d_in[4];
  const float* Wq   = (const float*)d_in[5];
  const float* Wk   = (const float*)d_in[6];
  const float* Wv   = (const float*)d_in[7];
  const float* Wo   = (const float*)d_in[8];
  const float* bo   = (const float*)d_in[9];
  const float* ln2g = (const float*)d_in[10];
  const float* ln2b = (const float*)d_in[11];
  const float* W1   = (const float*)d_in[12];
  const float* b1   = (const float*)d_in[13];
  const float* W2   = (const float*)d_in[14];
  const float* b2   = (const float*)d_in[15];
  const float* lnfg = (const float*)d_in[16];
  const float* lnfb = (const float*)d_in[17];

  char* ws = (char*)d_ws;
  float* h  = (float*)(ws);                      // 134217728 B
  u16* yb   = (u16*)(ws + 134217728ull);         // 67108864 B
  u16* qb   = (u16*)(ws + 201326592ull);         // q,k,v contiguous
  u16* kb   = (u16*)(ws + 268435456ull);
  u16* vb   = (u16*)(ws + 335544320ull);
  u16* cb   = (u16*)(ws + 402653184ull);
  u16* act  = qb;                                // overlays qb..cb
  u16* wqkvT= (u16*)(ws + 469762048ull);         // [L][3][D][D] = 6 MB
  u16* woT  = (u16*)(ws + 476053504ull);         // [L][D][D] = 2 MB
  u16* w1T  = (u16*)(ws + 478150656ull);         // 8 MB
  u16* w2T  = (u16*)(ws + 486539264ull);         // 8 MB
  float* pe = (float*)(ws + 494927872ull);       // 1 MB

  dim3 tb(32,8);
  pe_kernel<<<S_, D_, 0, stream>>>(pe);
  transpose_bf16<<<dim3(D_/32, D_/32, L_), tb, 0, stream>>>(Wq, wqkvT,            D_, D_, (size_t)3*D_*D_);
  transpose_bf16<<<dim3(D_/32, D_/32, L_), tb, 0, stream>>>(Wk, wqkvT + D_*D_,    D_, D_, (size_t)3*D_*D_);
  transpose_bf16<<<dim3(D_/32, D_/32, L_), tb, 0, stream>>>(Wv, wqkvT + 2*D_*D_,  D_, D_, (size_t)3*D_*D_);
  transpose_bf16<<<dim3(D_/32, D_/32, L_), tb, 0, stream>>>(Wo, woT,              D_, D_, (size_t)D_*D_);
  transpose_bf16<<<dim3(F_/32, D_/32, L_), tb, 0, stream>>>(W1, w1T, D_, F_, (size_t)D_*F_);
  transpose_bf16<<<dim3(D_/32, F_/32, L_), tb, 0, stream>>>(W2, w2T, F_, D_, (size_t)F_*D_);
  inproj_kernel<<<512, 512, 0, stream>>>(x, Win, bin, pe, h);

  ln_kernel<0><<<SB_/4, 256, 0, stream>>>(h, ln1g, ln1b, yb, nullptr);  // ln1[0]
  for (int l=0; l<L_; l++){
    gemm256n<0><<<dim3(6,512), 512, 0, stream>>>(yb, wqkvT + (size_t)l*3*D_*D_, nullptr, nullptr, qb, 1536, D_);
    attn_kernel<<<S_*H_, 256, 0, stream>>>(qb, kb, vb, cb);
    gemm256n<1><<<dim3(2,512), 512, 0, stream>>>(cb, woT + (size_t)l*D_*D_, bo + l*D_, h, nullptr, D_, D_);
    ln_kernel<0><<<SB_/4, 256, 0, stream>>>(h, ln2g + l*D_, ln2b + l*D_, yb, nullptr);
    gemm4w<2><<<dim3(16,512), 256, 0, stream>>>(yb, w1T + (size_t)l*D_*F_, b1 + l*F_, nullptr, act, F_, D_);
    gemm256n<1><<<dim3(2,512), 512, 0, stream>>>(act, w2T + (size_t)l*F_*D_, b2 + l*D_, h, nullptr, D_, F_);
    if (l < L_-1)
      ln_kernel<0><<<SB_/4, 256, 0, stream>>>(h, ln1g + (l+1)*D_, ln1b + (l+1)*D_, yb, nullptr);
  }
  ln_kernel<1><<<SB_/4, 256, 0, stream>>>(h, lnfg, lnfb, nullptr, (float*)d_out);
}